// Round 1
// baseline (637.980 us; speedup 1.0000x reference)
//
#include <hip/hip_runtime.h>
#include <stdint.h>

typedef unsigned short u16;
typedef unsigned int u32;
typedef __attribute__((ext_vector_type(8))) short bf16x8;
typedef __attribute__((ext_vector_type(4))) float f32x4;

#define S_LEN 4032
#define S_PAD 4096
#define DIMC  1536
#define NQKV  4608
#define HD    128
#define FRAME 448

// ---- workspace layout (bytes) ----
static const size_t OFF_FLAG  = 0;
static const size_t OFF_CANON = 256;                       // 74752 floats = 299008 B
static const size_t OFF_XB    = 524288;                    // 4096x1536 bf16
static const size_t OFF_WT    = OFF_XB  + 12582912;        // 4608x1536 bf16 (Wq|Wk|Wv transposed)
static const size_t OFF_WOT   = OFF_WT  + 14155776;        // 1536x1536 bf16 (Wo transposed)
static const size_t OFF_YQ    = OFF_WOT + 4718592;         // 4096x1536 bf16
static const size_t OFF_YK    = OFF_YQ  + 12582912;
static const size_t OFF_VT    = OFF_YK  + 12582912;        // 1536x4096 bf16 (V transposed)
static const size_t OFF_QH    = OFF_VT  + 12582912;        // 12x4032x128 bf16
static const size_t OFF_KH    = OFF_QH  + 12386304;
static const size_t OFF_AT    = OFF_KH  + 12386304;        // 4096x1536 bf16
static const size_t WS_NEED   = OFF_AT  + 12582912;        // ~102 MB

// canon float offsets
#define C_BQ 0
#define C_BO 4608
#define C_GQ 6144
#define C_GK 7680
#define C_FR 9216
#define C_TOT 74752

__device__ __forceinline__ u16 f2bf(float f) {
  union { float f; u32 u; } v; v.f = f;
  u32 u = v.u;
  u32 r = (u + 0x7fffu + ((u >> 16) & 1u)) >> 16;
  return (u16)r;
}
__device__ __forceinline__ float bf2f(u16 h) {
  union { float f; u32 u; } v; v.u = ((u32)h) << 16;
  return v.f;
}

__device__ __forceinline__ void gld_lds16(const void* g, void* l) {
  __builtin_amdgcn_global_load_lds(
      (const __attribute__((address_space(1))) void*)(uintptr_t)g,
      (__attribute__((address_space(3))) void*)(u32)(uintptr_t)l,
      16, 0, 0);
}

__device__ __forceinline__ f32x4 mfma16(bf16x8 a, bf16x8 b, f32x4 c) {
  return __builtin_amdgcn_mfma_f32_16x16x32_bf16(a, b, c, 0, 0, 0);
}

// ---------------- dtype detection ----------------
// fp32 data: even uint16s are mantissa halves -> random "exponent" bits.
// bf16 data: even uint16s are N(0,1) bf16 -> exponent <= ~130.
__global__ void detect_dtype(const u16* __restrict__ x, int* __restrict__ flag) {
  __shared__ int cnt;
  if (threadIdx.x == 0) cnt = 0;
  __syncthreads();
  int e = (x[2 * threadIdx.x] >> 7) & 0xff;
  if (e > 150) atomicAdd(&cnt, 1);
  __syncthreads();
  if (threadIdx.x == 0) *flag = (cnt >= 8) ? 1 : 0;  // 1 = fp32 inputs, 0 = bf16
}

// ---------------- small tensors -> canonical fp32 ----------------
__global__ void prep_small(const void* bq, const void* bk, const void* bv, const void* bo,
                           const void* gq, const void* gk, const void* fr,
                           float* __restrict__ canon, const int* __restrict__ flagp) {
  int fl = *flagp;
  for (int i = blockIdx.x * 256 + threadIdx.x; i < C_TOT; i += gridDim.x * 256) {
    const void* src; int j;
    if      (i < 1536) { src = bq; j = i; }
    else if (i < 3072) { src = bk; j = i - 1536; }
    else if (i < 4608) { src = bv; j = i - 3072; }
    else if (i < 6144) { src = bo; j = i - 4608; }
    else if (i < 7680) { src = gq; j = i - 6144; }
    else if (i < 9216) { src = gk; j = i - 7680; }
    else               { src = fr; j = i - 9216; }
    canon[i] = fl ? ((const float*)src)[j] : bf2f(((const u16*)src)[j]);
  }
}

// ---------------- x -> bf16, pad rows to 4096 with zeros ----------------
__global__ void convert_x(const void* __restrict__ xin, u16* __restrict__ xb,
                          const int* __restrict__ flagp) {
  int fl = *flagp;
  int i = blockIdx.x * 256 + threadIdx.x;   // chunk of 8 elements
  if (i >= (S_PAD * DIMC) / 8) return;
  size_t base = (size_t)i * 8;
  int row = (int)(base / DIMC);
  union { u16 h[8]; uint4 v; } u;
  if (row < S_LEN) {
    if (fl) {
      const float* xf = (const float*)xin + base;
      #pragma unroll
      for (int j = 0; j < 8; j++) u.h[j] = f2bf(xf[j]);
    } else {
      const u16* xh = (const u16*)xin + base;
      #pragma unroll
      for (int j = 0; j < 8; j++) u.h[j] = xh[j];
    }
  } else {
    #pragma unroll
    for (int j = 0; j < 8; j++) u.h[j] = 0;
  }
  ((uint4*)xb)[i] = u.v;
}

// ---------------- W (K x N) -> Wt (N x K) bf16 ----------------
__global__ void transpose_w(const void* Wq, const void* Wk, const void* Wv, const void* Wo,
                            u16* __restrict__ wqkvt, u16* __restrict__ wot,
                            const int* __restrict__ flagp) {
  int fl = *flagp;
  int z = blockIdx.z;
  const void* W = (z == 0) ? Wq : (z == 1) ? Wk : (z == 2) ? Wv : Wo;
  u16* dst = (z < 3) ? (wqkvt + (size_t)z * DIMC * DIMC) : wot;
  __shared__ float tile[32][33];
  int tx = threadIdx.x, ty = threadIdx.y;
  int c = blockIdx.x * 32 + tx;
  #pragma unroll
  for (int i = 0; i < 4; i++) {
    int r = blockIdx.y * 32 + ty + i * 8;
    float v = fl ? ((const float*)W)[(size_t)r * DIMC + c]
                 : bf2f(((const u16*)W)[(size_t)r * DIMC + c]);
    tile[ty + i * 8][tx] = v;
  }
  __syncthreads();
  int k = blockIdx.y * 32 + tx;
  #pragma unroll
  for (int i = 0; i < 4; i++) {
    int n = blockIdx.x * 32 + ty + i * 8;
    dst[(size_t)n * DIMC + k] = f2bf(tile[tx][ty + i * 8]);
  }
}

// ---------------- GEMM: C(MxN) = A(MxK) @ Bt(NxK)^T + bias ----------------
// MODE 0: N=4608 fused QKV epilogue -> Yq/Yk bf16 row-major, V written transposed bf16
// MODE 1: N=1536 output epilogue -> d_out (fp32 or bf16 per flag), rows guarded < 4032
template <int MODE>
__launch_bounds__(256, 2)
__global__ void gemm_bt(const u16* __restrict__ A, const u16* __restrict__ Bt,
                        const float* __restrict__ canon,
                        u16* __restrict__ Yq, u16* __restrict__ Yk, u16* __restrict__ Vt,
                        void* __restrict__ Out, const int* __restrict__ flagp) {
  const int bm0 = blockIdx.y * 128, bn0 = blockIdx.x * 128;
  const int tid = threadIdx.x, wave = tid >> 6, lane = tid & 63;
  const int wm = wave >> 1, wn = wave & 1;
  const int l15 = lane & 15, l4 = lane >> 4;
  __shared__ u16 sA[128 * 64];
  __shared__ u16 sB[128 * 64];
  f32x4 acc[4][4];
  #pragma unroll
  for (int i = 0; i < 4; i++)
    #pragma unroll
    for (int j = 0; j < 4; j++) acc[i][j] = (f32x4){0.f, 0.f, 0.f, 0.f};

  const u16* Ab = A  + (size_t)(bm0 + (lane >> 3)) * DIMC + (lane & 7) * 8;
  const u16* Bb = Bt + (size_t)(bn0 + (lane >> 3)) * DIMC + (lane & 7) * 8;

  for (int kt = 0; kt < DIMC; kt += 64) {
    __syncthreads();
    #pragma unroll
    for (int c = 0; c < 4; c++) {
      int g = wave * 4 + c;
      gld_lds16(Ab + (size_t)g * 8 * DIMC + kt, (char*)sA + g * 1024);
      gld_lds16(Bb + (size_t)g * 8 * DIMC + kt, (char*)sB + g * 1024);
    }
    __syncthreads();
    #pragma unroll
    for (int ks = 0; ks < 2; ks++) {
      const int ko = ks * 32 + l4 * 8;
      bf16x8 av[4], bvv[4];
      #pragma unroll
      for (int mt = 0; mt < 4; mt++) av[mt]  = *(const bf16x8*)(sA + (wm * 64 + mt * 16 + l15) * 64 + ko);
      #pragma unroll
      for (int nt = 0; nt < 4; nt++) bvv[nt] = *(const bf16x8*)(sB + (wn * 64 + nt * 16 + l15) * 64 + ko);
      #pragma unroll
      for (int mt = 0; mt < 4; mt++)
        #pragma unroll
        for (int nt = 0; nt < 4; nt++)
          acc[mt][nt] = mfma16(av[mt], bvv[nt], acc[mt][nt]);
    }
  }

  const int gm0 = bm0 + wm * 64;
  const int gn0 = bn0 + wn * 64;
  if (MODE == 0) {
    #pragma unroll
    for (int nt = 0; nt < 4; nt++) {
      int gn = gn0 + nt * 16 + l15;
      float b = canon[C_BQ + gn];
      #pragma unroll
      for (int mt = 0; mt < 4; mt++) {
        int gm = gm0 + mt * 16 + l4 * 4;
        if (gn < 1536) {
          #pragma unroll
          for (int r = 0; r < 4; r++)
            Yq[(size_t)(gm + r) * DIMC + gn] = f2bf(acc[mt][nt][r] + b);
        } else if (gn < 3072) {
          int g2 = gn - 1536;
          #pragma unroll
          for (int r = 0; r < 4; r++)
            Yk[(size_t)(gm + r) * DIMC + g2] = f2bf(acc[mt][nt][r] + b);
        } else {
          int g2 = gn - 3072;
          u32 lo = (u32)f2bf(acc[mt][nt][0] + b) | ((u32)f2bf(acc[mt][nt][1] + b) << 16);
          u32 hi = (u32)f2bf(acc[mt][nt][2] + b) | ((u32)f2bf(acc[mt][nt][3] + b) << 16);
          uint2 pk; pk.x = lo; pk.y = hi;
          *(uint2*)(Vt + (size_t)g2 * S_PAD + gm) = pk;
        }
      }
    }
  } else {
    const int fl = *flagp;
    #pragma unroll
    for (int nt = 0; nt < 4; nt++) {
      int gn = gn0 + nt * 16 + l15;
      float b = canon[C_BO + gn];
      #pragma unroll
      for (int mt = 0; mt < 4; mt++) {
        int gm = gm0 + mt * 16 + l4 * 4;
        #pragma unroll
        for (int r = 0; r < 4; r++) {
          int gr = gm + r;
          if (gr < S_LEN) {
            float v = acc[mt][nt][r] + b;
            if (fl) ((float*)Out)[(size_t)gr * DIMC + gn] = v;
            else    ((u16*)Out)[(size_t)gr * DIMC + gn] = f2bf(v);
          }
        }
      }
    }
  }
}

// ---------------- fused RMSNorm (over 1536) + RoPE, -> [head][s][128] bf16 ----------------
__global__ void norm_rope(const u16* __restrict__ Y, const float* __restrict__ g,
                          const float* __restrict__ fr, u16* __restrict__ Oh) {
  const int s = blockIdx.x;
  const int tid = threadIdx.x, wave = tid >> 6, lane = tid & 63;
  __shared__ float row[DIMC];
  __shared__ float cs[64], sn[64];
  __shared__ float red[4];
  float ss = 0.f;
  for (int i = tid; i < DIMC; i += 256) {
    float v = bf2f(Y[(size_t)s * DIMC + i]);
    row[i] = v; ss += v * v;
  }
  #pragma unroll
  for (int d = 32; d; d >>= 1) ss += __shfl_down(ss, d, 64);
  if (lane == 0) red[wave] = ss;
  if (tid < 64) {
    int f_ = s / FRAME, hh = (s % FRAME) / 28, ww = s % 28;
    float a;
    if (tid < 22)      a = fr[f_ * 64 + tid];
    else if (tid < 43) a = fr[hh * 64 + tid];
    else               a = fr[ww * 64 + tid];
    float si, co;
    __sincosf(a, &si, &co);
    cs[tid] = co; sn[tid] = si;
  }
  __syncthreads();
  float rms = rsqrtf((red[0] + red[1] + red[2] + red[3]) * (1.f / 1536.f) + 1e-6f);
  for (int p = tid; p < 768; p += 256) {
    int head = p >> 6, jj = p & 63;
    float xr = row[2 * p]     * rms * g[2 * p];
    float xi = row[2 * p + 1] * rms * g[2 * p + 1];
    float c = cs[jj], s_ = sn[jj];
    u32 pk = (u32)f2bf(xr * c - xi * s_) | ((u32)f2bf(xr * s_ + xi * c) << 16);
    *(u32*)(Oh + ((size_t)head * S_LEN + s) * HD + 2 * jj) = pk;
  }
}

// ---------------- flash attention, frame-causal ----------------
__launch_bounds__(256, 2)
__global__ void attn_kernel(const u16* __restrict__ Qh, const u16* __restrict__ Kh,
                            const u16* __restrict__ Vt, u16* __restrict__ Ab) {
  const int h = blockIdx.y;
  const int qt = 62 - blockIdx.x;          // heavy blocks first
  const int q0 = qt * 64;
  const int nkv = (q0 / FRAME + 1) * (FRAME / 64);
  const int tid = threadIdx.x, wave = tid >> 6, lane = tid & 63;
  const int l15 = lane & 15, l4 = lane >> 4;
  __shared__ u16 sK[64 * 128];
  __shared__ u16 sV[128 * 64];
  __shared__ u16 sP[4][16 * 64];

  bf16x8 qf[4];
  {
    const u16* qb = Qh + ((size_t)h * S_LEN + q0 + wave * 16 + l15) * HD + l4 * 8;
    #pragma unroll
    for (int ks = 0; ks < 4; ks++) qf[ks] = *(const bf16x8*)(qb + ks * 32);
  }
  f32x4 o[8];
  #pragma unroll
  for (int i = 0; i < 8; i++) o[i] = (f32x4){0.f, 0.f, 0.f, 0.f};
  float m_i[4], l_i[4];
  #pragma unroll
  for (int r = 0; r < 4; r++) { m_i[r] = -1e30f; l_i[r] = 0.f; }
  const float scale = 0.08838834764831845f;  // 1/sqrt(128)

  const u16* kb0 = Kh + (size_t)h * S_LEN * HD;
  const u16* vb0 = Vt + (size_t)h * HD * S_PAD;

  for (int t = 0; t < nkv; ++t) {
    __syncthreads();
    {
      const u16* kb = kb0 + (size_t)t * 64 * HD;
      const u16* vb = vb0 + t * 64;
      #pragma unroll
      for (int c = 0; c < 4; c++) {
        int gidx = wave * 4 + c;
        gld_lds16(kb + gidx * 512 + lane * 8, (char*)sK + gidx * 1024);
        gld_lds16(vb + (size_t)(gidx * 8 + (lane >> 3)) * S_PAD + (lane & 7) * 8,
                  (char*)sV + gidx * 1024);
      }
    }
    __syncthreads();

    f32x4 sf[4];
    #pragma unroll
    for (int nt = 0; nt < 4; nt++) sf[nt] = (f32x4){0.f, 0.f, 0.f, 0.f};
    #pragma unroll
    for (int ks = 0; ks < 4; ks++) {
      const int ko = ks * 32 + l4 * 8;
      #pragma unroll
      for (int nt = 0; nt < 4; nt++) {
        bf16x8 kf = *(const bf16x8*)(sK + (nt * 16 + l15) * 128 + ko);
        sf[nt] = mfma16(qf[ks], kf, sf[nt]);
      }
    }
    // online softmax (rows live in one 16-lane group; cols reduce via xor shuffles)
    float mloc[4];
    #pragma unroll
    for (int r = 0; r < 4; r++) {
      float a0 = sf[0][r] * scale, a1 = sf[1][r] * scale;
      float a2 = sf[2][r] * scale, a3 = sf[3][r] * scale;
      sf[0][r] = a0; sf[1][r] = a1; sf[2][r] = a2; sf[3][r] = a3;
      mloc[r] = fmaxf(fmaxf(a0, a1), fmaxf(a2, a3));
    }
    #pragma unroll
    for (int d = 1; d < 16; d <<= 1)
      #pragma unroll
      for (int r = 0; r < 4; r++)
        mloc[r] = fmaxf(mloc[r], __shfl_xor(mloc[r], d, 64));
    float alpha[4], rs[4];
    #pragma unroll
    for (int r = 0; r < 4; r++) {
      float mn = fmaxf(m_i[r], mloc[r]);
      alpha[r] = __expf(m_i[r] - mn);
      m_i[r] = mn;
      float p0 = __expf(sf[0][r] - mn), p1 = __expf(sf[1][r] - mn);
      float p2 = __expf(sf[2][r] - mn), p3 = __expf(sf[3][r] - mn);
      sf[0][r] = p0; sf[1][r] = p1; sf[2][r] = p2; sf[3][r] = p3;
      rs[r] = p0 + p1 + p2 + p3;
    }
    #pragma unroll
    for (int d = 1; d < 16; d <<= 1)
      #pragma unroll
      for (int r = 0; r < 4; r++)
        rs[r] += __shfl_xor(rs[r], d, 64);
    #pragma unroll
    for (int r = 0; r < 4; r++) l_i[r] = l_i[r] * alpha[r] + rs[r];
    #pragma unroll
    for (int i = 0; i < 8; i++)
      #pragma unroll
      for (int r = 0; r < 4; r++) o[i][r] *= alpha[r];

    // P: C-layout -> LDS -> A-layout (m120-verified round trip)
    u16* pw = sP[wave];
    #pragma unroll
    for (int nt = 0; nt < 4; nt++)
      #pragma unroll
      for (int r = 0; r < 4; r++)
        pw[(l4 * 4 + r) * 64 + nt * 16 + l15] = f2bf(sf[nt][r]);
    __syncthreads();
    #pragma unroll
    for (int ks = 0; ks < 2; ks++) {
      bf16x8 pa = *(const bf16x8*)(pw + l15 * 64 + ks * 32 + l4 * 8);
      #pragma unroll
      for (int vt_ = 0; vt_ < 8; vt_++) {
        bf16x8 vf = *(const bf16x8*)(sV + (vt_ * 16 + l15) * 64 + ks * 32 + l4 * 8);
        o[vt_] = mfma16(pa, vf, o[vt_]);
      }
    }
  }

  float inv[4];
  #pragma unroll
  for (int r = 0; r < 4; r++) inv[r] = 1.f / l_i[r];
  int row0 = q0 + wave * 16 + l4 * 4;
  #pragma unroll
  for (int i = 0; i < 8; i++)
    #pragma unroll
    for (int r = 0; r < 4; r++)
      Ab[(size_t)(row0 + r) * DIMC + h * HD + i * 16 + l15] = f2bf(o[i][r] * inv[r]);
}

extern "C" void kernel_launch(void* const* d_in, const int* in_sizes, int n_in,
                              void* d_out, int out_size, void* d_ws, size_t ws_size,
                              hipStream_t stream) {
  if (ws_size < WS_NEED) return;  // workspace too small: fail loudly (output stays poisoned)
  char* ws = (char*)d_ws;
  int*   flag  = (int*)(ws + OFF_FLAG);
  float* canon = (float*)(ws + OFF_CANON);
  u16* xb    = (u16*)(ws + OFF_XB);
  u16* wqkvt = (u16*)(ws + OFF_WT);
  u16* wot   = (u16*)(ws + OFF_WOT);
  u16* yq    = (u16*)(ws + OFF_YQ);
  u16* yk    = (u16*)(ws + OFF_YK);
  u16* vt    = (u16*)(ws + OFF_VT);
  u16* qh    = (u16*)(ws + OFF_QH);
  u16* kh    = (u16*)(ws + OFF_KH);
  u16* ab    = (u16*)(ws + OFF_AT);

  const void* x  = d_in[0];
  const void* fr = d_in[3];
  const void* Wq = d_in[4];  const void* bq = d_in[5];
  const void* Wk = d_in[6];  const void* bk = d_in[7];
  const void* Wv = d_in[8];  const void* bv = d_in[9];
  const void* Wo = d_in[10]; const void* bo = d_in[11];
  const void* gq = d_in[12]; const void* gk = d_in[13];

  detect_dtype<<<1, 256, 0, stream>>>((const u16*)x, flag);
  prep_small<<<292, 256, 0, stream>>>(bq, bk, bv, bo, gq, gk, fr, canon, flag);
  convert_x<<<3072, 256, 0, stream>>>(x, xb, flag);
  transpose_w<<<dim3(48, 48, 4), dim3(32, 8), 0, stream>>>(Wq, Wk, Wv, Wo, wqkvt, wot, flag);
  gemm_bt<0><<<dim3(36, 32), 256, 0, stream>>>(xb, wqkvt, canon, yq, yk, vt, nullptr, flag);
  norm_rope<<<4032, 256, 0, stream>>>(yq, canon + C_GQ, canon + C_FR, qh);
  norm_rope<<<4032, 256, 0, stream>>>(yk, canon + C_GK, canon + C_FR, kh);
  attn_kernel<<<dim3(63, 12), 256, 0, stream>>>(qh, kh, vt, ab);
  gemm_bt<1><<<dim3(12, 32), 256, 0, stream>>>(ab, wot, canon, nullptr, nullptr, nullptr, d_out, flag);
}